// Round 18
// baseline (140.129 us; speedup 1.0000x reference)
//
#include <hip/hip_runtime.h>
#include <math.h>

#define EPS 1e-5f

typedef __attribute__((ext_vector_type(8))) _Float16 f16x8;
typedef __attribute__((ext_vector_type(4))) float f32x4;
typedef __attribute__((ext_vector_type(2))) __fp16 fp16x2;

union H8u { ushort4 u[2]; uint4 q; f16x8 h; };
union PKu { fp16x2 h; unsigned int u; };
union U8u { unsigned short us[8]; uint4 q; };

__device__ __forceinline__ float sigmoidf_(float x){ return 1.f/(1.f+__expf(-x)); }

__device__ __forceinline__ unsigned short f2h(float f){
  union { _Float16 h; unsigned short u; } c;
  c.h = (_Float16)f;            // v_cvt_f16_f32, RNE
  return c.u;
}

// block-wide reduction of two accumulators; blockDim.x must be a multiple of 64
__device__ __forceinline__ void block_reduce2(float& s, float& s2){
  __shared__ float ls[16], ls2[16];
  #pragma unroll
  for (int off = 32; off; off >>= 1){
    s  += __shfl_down(s, off);
    s2 += __shfl_down(s2, off);
  }
  int wid = threadIdx.x >> 6, lane = threadIdx.x & 63;
  int nw = blockDim.x >> 6;
  if (lane == 0){ ls[wid] = s; ls2[wid] = s2; }
  __syncthreads();
  if (threadIdx.x == 0){
    float a = ls[0], b = ls2[0];
    for (int i = 1; i < nw; i++){ a += ls[i]; b += ls2[i]; }
    ls[0] = a; ls2[0] = b;
  }
  __syncthreads();
  s = ls[0]; s2 = ls2[0];
}

// ---- weight repack element generators ----
__device__ __forceinline__ unsigned short wffP_elem(const float* __restrict__ w, int Cin, int idx){
  int NCH = Cin >> 5;
  int per_tap = NCH << 9;
  int e = idx & 7, lane = (idx >> 3) & 63, chunk = (idx >> 9) % NCH;
  int tap = (idx / per_tap) % 9, coB = idx / (9 * per_tap);
  int lg = lane >> 4, lr = lane & 15;
  int co = coB * 16 + lr;
  int ch = chunk * 32 + ((e < 4) ? lg * 4 + e : 16 + lg * 4 + e - 4);
  return f2h(w[((long)co * Cin + ch) * 9 + tap]);
}

__device__ __forceinline__ unsigned short wffF_elem(const float* __restrict__ w, int Cin, int idx){
  int NCH = Cin >> 5;
  int per_tap = NCH << 9;
  int per_p = 8 * 4 * per_tap;
  int e = idx & 7, lane = (idx >> 3) & 63, chunk = (idx >> 9) % NCH;
  int tap = (idx / per_tap) % 4;
  int coB = (idx / (4 * per_tap)) % 8;
  int p = idx / per_p;
  int ph = p >> 1, pw = p & 1, kr = tap >> 1, kc = tap & 1;
  int lg = lane >> 4, lr = lane & 15;
  int co = coB * 16 + lr;
  int ch = chunk * 32 + ((e < 4) ? lg * 4 + e : 16 + lg * 4 + e - 4);
  const float* wb = &w[((long)co * Cin + ch) * 9];
  float sum = 0.f;
  for (int kh = 0; kh < 3; kh++){
    bool rok = (ph == 0) ? (kr == 0 ? kh == 0 : kh >= 1)
                         : (kr == 0 ? kh <= 1 : kh == 2);
    if (!rok) continue;
    for (int kw = 0; kw < 3; kw++){
      bool cok = (pw == 0) ? (kc == 0 ? kw == 0 : kw >= 1)
                           : (kc == 0 ? kw <= 1 : kw == 2);
      if (cok) sum += wb[kh * 3 + kw];
    }
  }
  return f2h(sum);
}

// Merged: PE/cast/transpose for y (dual) + s, AND all four weight repacks.
__global__ __launch_bounds__(256) void prep_all_kernel(
    const float* __restrict__ y, const float* __restrict__ s,
    unsigned short* __restrict__ y_peT, unsigned short* __restrict__ yT,
    unsigned short* __restrict__ s_peT,
    const float* __restrict__ wby, const float* __restrict__ wbs,
    const float* __restrict__ wg,  const float* __restrict__ wp,
    unsigned short* __restrict__ oby, unsigned short* __restrict__ obs,
    unsigned short* __restrict__ og,  unsigned short* __restrict__ op){
  __shared__ unsigned short tile[64][72];
  __shared__ unsigned short tile2[64][72];
  int bid = blockIdx.x;
  int tid = threadIdx.x;
  if (bid >= 1536){
    const int T0 = 294912, T1 = T0 + 147456, T2 = T1 + 524288, T3 = T2 + 262144;
    for (int idx = (bid - 1536) * 256 + tid; idx < T3; idx += 300 * 256){
      if (idx < T0)       oby[idx]      = wffP_elem(wby, 256, idx);
      else if (idx < T1)  obs[idx - T0] = wffP_elem(wbs, 128, idx - T0);
      else if (idx < T2)  og[idx - T1]  = wffF_elem(wg, 256, idx - T1);
      else                op[idx - T2]  = wffF_elem(wp, 128, idx - T2);
    }
    return;
  }
  const float* x; unsigned short *xt, *xt2;
  int C, L, half, bx, by, bz;
  if (bid < 512){
    x = y; xt = y_peT; xt2 = yT; C = 256; L = 4096; half = 128;
    bx = bid & 63; by = (bid >> 6) & 3; bz = bid >> 8;
  } else {
    int b2 = bid - 512;
    x = s; xt = s_peT; xt2 = nullptr; C = 128; L = 16384; half = 64;
    bx = b2 & 255; by = (b2 >> 8) & 1; bz = b2 >> 9;
  }
  int c0 = by * 64, l0 = bx * 64;
  int b = bz;
  const float l2r = 13.28771237954945f; // log2(10000)
  #pragma unroll
  for (int i = 0; i < 4; i++){
    int id = tid + i * 256;
    int c = id >> 4, ch = (id & 15) * 4;
    int cg = c0 + c;
    float4 v = *(const float4*)&x[((long)b * C + cg) * L + l0 + ch];
    int d = cg < half ? cg : cg - half;
    float rate = exp2f(-l2r * (float)d / (float)half);
    float a0 = (float)(l0 + ch) * rate;
    float pe0, pe1, pe2, pe3;
    if (cg < half){ pe0 = sinf(a0); pe1 = sinf(a0 + rate); pe2 = sinf(a0 + 2.f*rate); pe3 = sinf(a0 + 3.f*rate); }
    else          { pe0 = cosf(a0); pe1 = cosf(a0 + rate); pe2 = cosf(a0 + 2.f*rate); pe3 = cosf(a0 + 3.f*rate); }
    ushort4 o;
    o.x = f2h(v.x + pe0); o.y = f2h(v.y + pe1);
    o.z = f2h(v.z + pe2); o.w = f2h(v.w + pe3);
    *(ushort4*)&tile[c][ch] = o;
    if (xt2){
      ushort4 o2;
      o2.x = f2h(v.x); o2.y = f2h(v.y); o2.z = f2h(v.z); o2.w = f2h(v.w);
      *(ushort4*)&tile2[c][ch] = o2;
    }
  }
  __syncthreads();
  #pragma unroll
  for (int i = 0; i < 2; i++){
    int id = tid + i * 256;
    int l = id >> 3, ch = (id & 7) * 8;
    ushort4 a, bq;
    a.x = tile[ch+0][l]; a.y = tile[ch+1][l]; a.z = tile[ch+2][l]; a.w = tile[ch+3][l];
    bq.x = tile[ch+4][l]; bq.y = tile[ch+5][l]; bq.z = tile[ch+6][l]; bq.w = tile[ch+7][l];
    unsigned short* opt = &xt[((long)b * L + l0 + l) * C + c0 + ch];
    *(ushort4*)opt = a;
    *(ushort4*)(opt + 4) = bq;
    if (xt2){
      ushort4 a2, b2;
      a2.x = tile2[ch+0][l]; a2.y = tile2[ch+1][l]; a2.z = tile2[ch+2][l]; a2.w = tile2[ch+3][l];
      b2.x = tile2[ch+4][l]; b2.y = tile2[ch+5][l]; b2.z = tile2[ch+6][l]; b2.w = tile2[ch+7][l];
      unsigned short* op2 = &xt2[((long)b * L + l0 + l) * C + c0 + ch];
      *(ushort4*)op2 = a2;
      *(ushort4*)(op2 + 4) = b2;
    }
  }
}

// Implicit-GEMM MFMA conv body. Block = 4 waves, 64co x 64sp.
// STATS=1: per-block per-channel partial sum/sumsq (deterministic slots;
// partial stride 256 for UP convs, 64 for blues).
template<int NTAP, int CSHIFT, int UP, int STATS>
__device__ __forceinline__ void conv_body(
    const unsigned short* __restrict__ xt, const unsigned short* __restrict__ wff,
    unsigned short* __restrict__ out,
    float* __restrict__ psum, float* __restrict__ psq, int which,
    int Hin, int Win, int stride, int Wout, int woutLog, int HWout,
    int bz, char* stage, int* rowIdx){
  constexpr int Cin = 8 << CSHIFT;
  constexpr int NCHUNK = 1 << (CSHIFT - 2);
  constexpr int PSTRIDE = UP ? 256 : 64;
  int tid = threadIdx.x;
  int lane = tid & 63, wid = tid >> 6;
  int lg = lane >> 4, lr = lane & 15;
  int b, par = 0;
  if (UP){ par = bz & 3; b = bz >> 2; } else b = bz;
  const unsigned short* xb = xt + (long)b * Hin * Win * Cin;
  int coB = blockIdx.y * 4 + wid;

  if (UP){
    int ph = par >> 1, pw = par & 1;
    int ii = blockIdx.x;
    int VH = 2 * Hin, VW = 2 * Win;
    for (int id = tid; id < NTAP * 64; id += 256){
      int tap = id >> 6, r = id & 63;
      int kr = tap >> 1, kc = tap & 1;
      int v = 2 * ii + (ph == 0 ? (kr == 0 ? -1 : 0) : (kr == 0 ? 0 : 2));
      v = v < 0 ? -v : (v >= VH ? 2 * VH - 2 - v : v);
      int u = 2 * r + (pw == 0 ? (kc == 0 ? -1 : 0) : (kc == 0 ? 0 : 2));
      u = u < 0 ? -u : (u >= VW ? 2 * VW - 2 - u : u);
      rowIdx[tap * 64 + r] = (v >> 1) * Win + (u >> 1);
    }
  } else {
    int sp0 = blockIdx.x * 64;
    for (int id = tid; id < NTAP * 64; id += 256){
      int tap = id >> 6, r = id & 63;
      int kh = tap / 3, kw = tap - kh * 3;
      int sp = sp0 + r;
      int oh = sp >> woutLog, ow = sp & (Wout - 1);
      int ih = oh * stride - 1 + kh;
      ih = ih < 0 ? -ih : (ih >= Hin ? 2 * Hin - 2 - ih : ih);
      int iw = ow * stride - 1 + kw;
      iw = iw < 0 ? -iw : (iw >= Win ? 2 * Win - 2 - iw : iw);
      rowIdx[tap * 64 + r] = ih * Win + iw;
    }
  }

  f32x4 acc[4];
  #pragma unroll
  for (int f = 0; f < 4; f++) acc[f] = (f32x4){0.f, 0.f, 0.f, 0.f};

  const unsigned short* wbase =
      wff + ((long)((UP ? par : 0) * 8 + coB) * NTAP) * (NCHUNK * 512) + lane * 8;

  for (int tap = 0; tap < NTAP; tap++){
    __syncthreads();
    #pragma unroll
    for (int i2 = 0; i2 < NCHUNK; i2++){
      int id = tid + (i2 << 8);
      int sp = id >> CSHIFT;
      int c8 = (id & ((1 << CSHIFT) - 1)) << 3;
      int chunk = c8 >> 5, c = c8 & 31;
      int lgb = (c & 15) >> 2, hoff = (c >> 4) & 1;
      uint4 g = *(const uint4*)&xb[(long)rowIdx[tap * 64 + sp] * Cin + c8];
      int slot = ((chunk * 4 + (sp >> 4)) * 64 + lgb * 16 + (sp & 15)) * 16
                 + hoff * 8 + chunk * 16;
      *(uint2*)(stage + slot)       = make_uint2(g.x, g.y);
      *(uint2*)(stage + slot + 256) = make_uint2(g.z, g.w);
    }
    __syncthreads();
    const unsigned short* wp = wbase + (long)tap * (NCHUNK * 512);
    #pragma unroll
    for (int ch = 0; ch < NCHUNK; ch++){
      H8u A; A.q = *(const uint4*)(wp + ch * 512);
      #pragma unroll
      for (int f = 0; f < 4; f++){
        H8u X; X.q = *(const uint4*)(stage + ((ch * 4 + f) * 64 + lane) * 16 + ch * 16);
        acc[f] = __builtin_amdgcn_mfma_f32_16x16x32_f16(A.h, X.h, acc[f], 0, 0, 0);
      }
    }
  }

  unsigned short* ob = out + (long)b * 128 * HWout;
  #pragma unroll
  for (int f = 0; f < 4; f++){
    int spl = f * 16 + lr;
    long opos;
    if (UP){
      int oh = 2 * blockIdx.x + (par >> 1);
      int ow = 2 * spl + (par & 1);
      opos = (long)oh * Wout + ow;
    } else opos = (long)blockIdx.x * 64 + spl;
    #pragma unroll
    for (int r = 0; r < 4; r++){
      int co = coB * 16 + lg * 4 + r;
      ob[(long)co * HWout + opos] = f2h(acc[f][r]);
    }
  }

  if constexpr (STATS){
    float ts[4], tq[4];
    #pragma unroll
    for (int r = 0; r < 4; r++){ ts[r] = 0.f; tq[r] = 0.f; }
    #pragma unroll
    for (int f = 0; f < 4; f++)
      #pragma unroll
      for (int r = 0; r < 4; r++){
        float hv = (float)(_Float16)acc[f][r];
        ts[r] += hv; tq[r] += hv * hv;
      }
    #pragma unroll
    for (int off = 1; off < 16; off <<= 1){
      #pragma unroll
      for (int r = 0; r < 4; r++){
        ts[r] += __shfl_xor(ts[r], off);
        tq[r] += __shfl_xor(tq[r], off);
      }
    }
    if (lr == 0){
      int strip = UP ? (blockIdx.x * 4 + par) : blockIdx.x;
      #pragma unroll
      for (int r = 0; r < 4; r++){
        int co = coB * 16 + lg * 4 + r;
        long pidx = (((long)which * 2 + b) * 128 + co) * PSTRIDE + strip;
        psum[pidx] = ts[r];
        psq[pidx]  = tq[r];
      }
    }
  }
}

// Merged blue convs (+ partial stats): grid (64, 2, 4); z<2 -> blue_y, else blue_s.
__global__ __launch_bounds__(256) void conv_blue_kernel(
    const unsigned short* __restrict__ y_peT, const unsigned short* __restrict__ s_peT,
    const unsigned short* __restrict__ wby, const unsigned short* __restrict__ wbs,
    unsigned short* __restrict__ qbuf, unsigned short* __restrict__ vbuf,
    float* __restrict__ psumB, float* __restrict__ psqB){
  __shared__ __align__(16) char stage[8 * 4112];
  __shared__ int rowIdx[9 * 64];
  int z = blockIdx.z;
  if (z < 2)
    conv_body<9,5,0,1>(y_peT, wby, qbuf, psumB, psqB, 0,
                       64, 64, 1, 64, 6, 4096, z, stage, rowIdx);
  else
    conv_body<9,4,0,1>(s_peT, wbs, vbuf, psumB, psqB, 1,
                       128, 128, 2, 64, 6, 4096, z - 2, stage, rowIdx);
}

// Merged upsample convs (+partial stats): grid (64, 2, 16); z<8 -> green, else purple.
__global__ __launch_bounds__(256) void conv_up_kernel(
    const unsigned short* __restrict__ yT, const unsigned short* __restrict__ mhaT,
    const unsigned short* __restrict__ wg, const unsigned short* __restrict__ wp,
    unsigned short* __restrict__ green_h, unsigned short* __restrict__ purple_h,
    float* __restrict__ psum, float* __restrict__ psq){
  __shared__ __align__(16) char stage[8 * 4112];
  __shared__ int rowIdx[4 * 64];
  int z = blockIdx.z;
  if (z < 8)
    conv_body<4,5,1,1>(yT, wg, green_h, psum, psq, 0,
                       64, 64, 1, 128, 7, 16384, z, stage, rowIdx);
  else
    conv_body<4,4,1,1>(mhaT, wp, purple_h, psum, psq, 1,
                       64, 64, 1, 128, 7, 16384, z - 8, stage, rowIdx);
}

// Normalize+SiLU using conv_blue's partial stats (no data re-read for stats).
// blocks [0,256): Q path -> coalesced transposed write via LDS tile.
// blocks [256,768): V path -> vectorized channel-major write.
__global__ __launch_bounds__(256) void qkv_transform_kernel(
    const unsigned short* __restrict__ qbuf, const unsigned short* __restrict__ vbuf,
    const float* __restrict__ psumB, const float* __restrict__ psqB,
    unsigned short* __restrict__ outT, unsigned short* __restrict__ outV){
  int bid = blockIdx.x;
  int tid = threadIdx.x;
  if (bid < 256){
    __shared__ unsigned short tile[32][137];
    __shared__ float sm[32], sr[32];
    int pt = bid & 31, h = (bid >> 5) & 3, bb = bid >> 7;
    int c_local = tid >> 3, i0 = tid & 7;
    int cg = h * 32 + c_local;
    long base = ((long)bb * 128 + cg) * 64;     // which=0 group = bb
    float s = 0.f, s2 = 0.f;
    #pragma unroll
    for (int k = 0; k < 8; k++){
      s  += psumB[base + i0 + k * 8];
      s2 += psqB[base + i0 + k * 8];
    }
    #pragma unroll
    for (int off = 1; off < 8; off <<= 1){
      s  += __shfl_xor(s, off);
      s2 += __shfl_xor(s2, off);
    }
    if (i0 == 0){
      float mean = s * (1.f / 4096.f);
      float var  = s2 * (1.f / 4096.f) - mean * mean;
      sm[c_local] = mean;
      sr[c_local] = rsqrtf(var + EPS);
    }
    __syncthreads();
    float mean = sm[c_local], rstd = sr[c_local];
    const unsigned short* qp = qbuf + ((long)bb * 128 + cg) * 4096 + pt * 128 + i0 * 16;
    H8u a, b2;
    a.q  = *(const uint4*)qp;
    b2.q = *(const uint4*)(qp + 8);
    #pragma unroll
    for (int j = 0; j < 8; j++){
      float t0 = ((float)a.h[j] - mean) * rstd;
      tile[c_local][i0 * 16 + j] = f2h(t0 * sigmoidf_(t0));
      float t1 = ((float)b2.h[j] - mean) * rstd;
      tile[c_local][i0 * 16 + 8 + j] = f2h(t1 * sigmoidf_(t1));
    }
    __syncthreads();
    int pos = tid >> 1, halfd = tid & 1;
    U8u w0, w1;
    #pragma unroll
    for (int k = 0; k < 8; k++) w0.us[k] = tile[halfd * 16 + k][pos];
    #pragma unroll
    for (int k = 0; k < 8; k++) w1.us[k] = tile[halfd * 16 + 8 + k][pos];
    unsigned short* op = outT + ((long)((bb * 4 + h) * 4096 + pt * 128 + pos)) * 32 + halfd * 16;
    *(uint4*)op = w0.q;
    *(uint4*)(op + 8) = w1.q;
  } else {
    int vb = bid - 256;                 // 0..511; two blocks per channel
    int bc = vb >> 1;
    long gbase = ((long)(2 + (bc >> 7)) * 128 + (bc & 127)) * 64;  // which=1
    float s = 0.f, s2 = 0.f;
    if (tid < 64){ s = psumB[gbase + tid]; s2 = psqB[gbase + tid]; }
    block_reduce2(s, s2);
    float mean = s * (1.f / 4096.f);
    float var  = s2 * (1.f / 4096.f) - mean * mean;
    float rstd = rsqrtf(var + EPS);
    long e0 = (long)vb * 2048 + tid * 8;
    H8u a; a.q = *(const uint4*)&vbuf[e0];
    H8u o;
    #pragma unroll
    for (int j = 0; j < 8; j++){
      float t = ((float)a.h[j] - mean) * rstd;
      o.h[j] = (_Float16)(t * sigmoidf_(t));
    }
    *(uint4*)&outV[e0] = o.q;
  }
}

// MFMA flash attention (fp16), 4-way key-split, 64-key tiles, LDS double-buffer
// + V-XOR de-conflict + defer-max + pre-scaled Q + deferred l reduction.
__global__ __launch_bounds__(1024, 8) void flash_attn_kernel(
    const unsigned short* __restrict__ qk,
    const unsigned short* __restrict__ vt,
    unsigned short* __restrict__ mhaT, int N){
  __shared__ float smem[16384];                // 64 KB: 2 x (4 splits x 8KB)
  unsigned short* sstage = (unsigned short*)smem;
  const float SCALE2 = 0.25503257066404493f;   // (1/sqrt(32)) * log2(e)

  int bh = blockIdx.y;
  int b = bh >> 2, h = bh & 3;
  int tid = threadIdx.x;
  int ks = tid >> 8;                 // key-split 0..3
  int t256 = tid & 255;
  int qg = (tid >> 6) & 3;           // query-group within split
  int lane = tid & 63;
  int lg = lane >> 4, lr = lane & 15;
  const unsigned short* qbase = qk + (long)bh * N * 32;
  const unsigned short* vbase = vt + (long)(b * 128 + h * 32) * N;
  int ksu = ks * 4096;               // ushort offset of this split's 8KB stage

  int q0w = blockIdx.x * 64 + qg * 16;
  f16x8 qf;
  {
    const unsigned short* qp = qbase + (long)(q0w + lr) * 32 + lg * 4;
    H8u Q;
    Q.u[0] = *(const ushort4*)qp;
    Q.u[1] = *(const ushort4*)(qp + 16);
    qf = Q.h;
    const _Float16 sc = (_Float16)SCALE2;
    #pragma unroll
    for (int j = 0; j < 8; j++) qf[j] = qf[j] * sc;
  }

  int skey = t256 >> 2, sq4 = t256 & 3;        // K: key row, d-quarter (2-way = free)
  int kdst = ksu + (((skey >> 4) * 4 + (sq4 & 1) * 2) * 16 + (skey & 15)) * 8 + (sq4 >> 1) * 4;
  int sd = t256 >> 3, soct = t256 & 7;         // V: d row, key-octet
  int vx = (soct >> 2) * 2 + (soct & 1);
  int vdst = ksu + 2048 +
      ((((soct >> 2) * 2 + (sd >> 4)) * 4 + (soct & 1) * 2) * 16 + ((sd & 15) ^ vx)) * 8 +
      ((soct >> 1) & 1) * 4;

  float m_run = -1e30f, l_run = 0.f;           // l_run is PER-LANE partial
  f32x4 acc0 = {0.f,0.f,0.f,0.f}, acc1 = {0.f,0.f,0.f,0.f};

  const int NT = N >> 8;                       // 64-key tiles per split

  // prologue: stage tile 0 into buffer 0
  {
    int k0 = ks * NT * 64;
    uint4 kl = *(const uint4*)(qbase + (long)(k0 + skey) * 32 + sq4 * 8);
    *(uint2*)(&sstage[kdst])       = make_uint2(kl.x, kl.y);
    *(uint2*)(&sstage[kdst + 128]) = make_uint2(kl.z, kl.w);
    uint4 vl = *(const uint4*)(vbase + (long)sd * N + k0 + soct * 8);
    *(uint2*)(&sstage[vdst])       = make_uint2(vl.x, vl.y);
    *(uint2*)(&sstage[vdst + 128]) = make_uint2(vl.z, vl.w);
  }
  __syncthreads();

  for (int t = 0; t < NT; t++){
    int bufc = (t & 1) << 14;                  // 16384 ushorts per buffer
    int bufn = ((t + 1) & 1) << 14;
    uint4 kl, vl;
    bool have_next = (t + 1 < NT);
    if (have_next){
      int k0n = (ks * NT + t + 1) * 64;
      kl = *(const uint4*)(qbase + (long)(k0n + skey) * 32 + sq4 * 8);
      vl = *(const uint4*)(vbase + (long)sd * N + k0n + soct * 8);
    }

    // compute tile t from buffer bufc
    f32x4 st[4];
    #pragma unroll
    for (int kb = 0; kb < 4; kb++){
      H8u K;
      K.q = *(const uint4*)(&sstage[bufc + ksu + (kb * 64 + lane) * 8]);
      st[kb] = __builtin_amdgcn_mfma_f32_16x16x32_f16(K.h, qf,
                  (f32x4){0.f,0.f,0.f,0.f}, 0, 0, 0);
    }

    float mk0 = fmaxf(fmaxf(fmaxf(st[0][0], st[0][1]), st[0][2]), st[0][3]);
    float mk1 = fmaxf(fmaxf(fmaxf(st[1][0], st[1][1]), st[1][2]), st[1][3]);
    float mk2 = fmaxf(fmaxf(fmaxf(st[2][0], st[2][1]), st[2][2]), st[2][3]);
    float mk3 = fmaxf(fmaxf(fmaxf(st[3][0], st[3][1]), st[3][2]), st[3][3]);
    float mt = fmaxf(fmaxf(fmaxf(mk0, mk1), mk2), mk3);
    mt = fmaxf(mt, __shfl_xor(mt, 16));
    mt = fmaxf(mt, __shfl_xor(mt, 32));

    bool noresc = __all(mt <= m_run + 8.f);
    float m_new = noresc ? m_run : fmaxf(m_run, mt);

    float lt = 0.f;
    unsigned int pup[8];
    #pragma unroll
    for (int kb = 0; kb < 4; kb++)
      #pragma unroll
      for (int rp = 0; rp < 2; rp++){
        float p0 = __builtin_amdgcn_exp2f(st[kb][2*rp]   - m_new);
        float p1 = __builtin_amdgcn_exp2f(st[kb][2*rp+1] - m_new);
        lt += p0 + p1;
        PKu pk;
        pk.h = __builtin_amdgcn_cvt_pkrtz(p0, p1);
        pup[kb * 2 + rp] = pk.u;
      }

    if (noresc){
      l_run += lt;
    } else {
      float fscale = __builtin_amdgcn_exp2f(m_run - m_new);
      l_run = l_run * fscale + lt;               // fscale uniform per query group
      float fr[4];
      #pragma unroll
      for (int r = 0; r < 4; r++) fr[r] = __shfl(fscale, lg * 4 + r);
      #pragma unroll
      for (int r = 0; r < 4; r++){ acc0[r] *= fr[r]; acc1[r] *= fr[r]; }
      m_run = m_new;
    }

    #pragma unroll
    for (int m = 0; m < 2; m++){
      int xr = m * 2 + (lg >> 1);
      int laneV = lg * 16 + (lr ^ xr);
      H8u P, V0, V1;
      P.q = make_uint4(pup[4*m], pup[4*m+1], pup[4*m+2], pup[4*m+3]);
      V0.q = *(const uint4*)(&sstage[bufc + ksu + 2048 + ((m * 2 + 0) * 64 + laneV) * 8]);
      V1.q = *(const uint4*)(&sstage[bufc + ksu + 2048 + ((m * 2 + 1) * 64 + laneV) * 8]);
      acc0 = __builtin_amdgcn_mfma_f32_16x16x32_f16(P.h, V0.h, acc0, 0, 0, 0);
      acc1 = __builtin_amdgcn_mfma_f32_16x16x32_f16(P.h, V1.h, acc1, 0, 0, 0);
    }

    // stage tile t+1 into the other buffer, then one barrier
    if (have_next){
      *(uint2*)(&sstage[bufn + kdst])       = make_uint2(kl.x, kl.y);
      *(uint2*)(&sstage[bufn + kdst + 128]) = make_uint2(kl.z, kl.w);
      *(uint2*)(&sstage[bufn + vdst])       = make_uint2(vl.x, vl.y);
      *(uint2*)(&sstage[bufn + vdst + 128]) = make_uint2(vl.z, vl.w);
    }
    __syncthreads();
  }

  // deferred l reduction across the 4 aliased lanes
  l_run += __shfl_xor(l_run, 16);
  l_run += __shfl_xor(l_run, 32);

  // ---- split merge in LDS ----
  float* accM = smem;                          // [qg][ks][16 q][33]
  float* mM   = smem + 8448;
  float* lM   = smem + 8704;
  #pragma unroll
  for (int r = 0; r < 4; r++){
    accM[((qg * 4 + ks) * 16 + (lg * 4 + r)) * 33 + lr]      = acc0[r];
    accM[((qg * 4 + ks) * 16 + (lg * 4 + r)) * 33 + 16 + lr] = acc1[r];
  }
  if (lg == 0){
    mM[(qg * 4 + ks) * 16 + lr] = m_run;
    lM[(qg * 4 + ks) * 16 + lr] = l_run;
  }
  __syncthreads();
  if (ks == 0){
    int q = lane >> 2, dc = lane & 3;
    float ms[4], es[4];
    float m = -1e30f;
    #pragma unroll
    for (int s = 0; s < 4; s++){ ms[s] = mM[(qg * 4 + s) * 16 + q]; m = fmaxf(m, ms[s]); }
    float l = 0.f;
    #pragma unroll
    for (int s = 0; s < 4; s++){
      es[s] = __builtin_amdgcn_exp2f(ms[s] - m);
      l += lM[(qg * 4 + s) * 16 + q] * es[s];
    }
    float inv = 1.f / l;
    float o[8];
    #pragma unroll
    for (int j = 0; j < 8; j++) o[j] = 0.f;
    #pragma unroll
    for (int s = 0; s < 4; s++){
      const float* ap = &accM[((qg * 4 + s) * 16 + q) * 33 + dc * 8];
      #pragma unroll
      for (int j = 0; j < 8; j++) o[j] += ap[j] * es[s];
    }
    ushort4 o0, o1;
    o0.x = f2h(o[0]*inv); o0.y = f2h(o[1]*inv); o0.z = f2h(o[2]*inv); o0.w = f2h(o[3]*inv);
    o1.x = f2h(o[4]*inv); o1.y = f2h(o[5]*inv); o1.z = f2h(o[6]*inv); o1.w = f2h(o[7]*inv);
    unsigned short* op = &mhaT[((long)b * N + q0w + q) * 128 + h * 32 + dc * 8];
    *(ushort4*)op = o0;
    *(ushort4*)(op + 4) = o1;
  }
}

// Collapse per-block upconv partials (deterministic)
__global__ __launch_bounds__(64) void stats3_kernel(
    const float* __restrict__ psum, const float* __restrict__ psq,
    float* __restrict__ statsbase){
  int blockch = blockIdx.x;
  int which = blockch >> 8, bc = blockch & 255;
  const float* ps = psum + (long)blockch * 256;
  const float* pq = psq  + (long)blockch * 256;
  float s = 0.f, s2 = 0.f;
  for (int i = threadIdx.x; i < 256; i += 64){ s += ps[i]; s2 += pq[i]; }
  #pragma unroll
  for (int off = 32; off; off >>= 1){
    s  += __shfl_down(s, off);
    s2 += __shfl_down(s2, off);
  }
  if (threadIdx.x == 0){
    float* sums = statsbase + which * 512;
    sums[bc] = s;
    sums[256 + bc] = s2;
  }
}

// Merged ILN finalize: blockIdx.z = 0 -> purple (sigmoid*gate), 1 -> green (silu).
__global__ __launch_bounds__(256) void iln_finalize2_kernel(
    const unsigned short* __restrict__ xg, const unsigned short* __restrict__ xp,
    const float* __restrict__ statsbase,
    const float* __restrict__ rho_p, const float* __restrict__ gamma_p,
    const float* __restrict__ beta_p,
    const float* __restrict__ rho_g, const float* __restrict__ gamma_g,
    const float* __restrict__ beta_g,
    const float* __restrict__ gate,
    float* __restrict__ out,
    int HW, int C){
  int zp = blockIdx.z;                 // 0 = purple, 1 = green
  int bc = blockIdx.y;
  int b = bc / C, c = bc % C;
  const float* sums   = statsbase + (zp ? 0 : 512);   // green at +0, purple at +512
  const float* sumsqs = sums + 256;

  // inline layer reduction over C channels of batch b
  float s = 0.f, s2 = 0.f;
  if (threadIdx.x < 128){
    int cc = b * C + threadIdx.x;
    s = sums[cc]; s2 = sumsqs[cc];
  }
  block_reduce2(s, s2);
  float lsum = s, lsumsq = s2;

  float n = (float)HW;
  float im = sums[bc] / n;
  float iv = (sumsqs[bc] / n - im * im) * (n / (n - 1.f));
  float ir = rsqrtf(iv + EPS);
  float n2 = n * (float)C;
  float lm = lsum / n2;
  float lv = (lsumsq / n2 - lm * lm) * (n2 / (n2 - 1.f));
  float lr = rsqrtf(lv + EPS);
  float r  = zp ? rho_g[c]   : rho_p[c];
  float g  = zp ? gamma_g[c] : gamma_p[c];
  float bb = zp ? beta_g[c]  : beta_p[c];

  const unsigned short* xp_ = (zp ? xg : xp) + (long)bc * HW;
  const float* gp = zp ? nullptr : (gate + (long)bc * HW);
  float* op = out + ((long)(b * 256 + (zp ? 128 : 0) + c)) * HW;
  int i0 = (blockIdx.x * 256 + threadIdx.x) * 8;
  H8u a; a.q = *(const uint4*)&xp_[i0];
  float4 o0, o1;
  float res[8];
  #pragma unroll
  for (int j = 0; j < 8; j++){
    float xv = (float)a.h[j];
    float t = r * (xv - im) * ir + (1.f - r) * (xv - lm) * lr;
    t = t * g + bb;
    float sg = sigmoidf_(t);
    res[j] = zp ? t * sg : sg;
  }
  if (!zp){
    float4 g0 = *(const float4*)&gp[i0];
    float4 g1 = *(const float4*)&gp[i0 + 4];
    res[0] *= g0.x; res[1] *= g0.y; res[2] *= g0.z; res[3] *= g0.w;
    res[4] *= g1.x; res[5] *= g1.y; res[6] *= g1.z; res[7] *= g1.w;
  }
  o0.x = res[0]; o0.y = res[1]; o0.z = res[2]; o0.w = res[3];
  o1.x = res[4]; o1.y = res[5]; o1.z = res[6]; o1.w = res[7];
  *(float4*)&op[i0] = o0;
  *(float4*)&op[i0 + 4] = o1;
}

extern "C" void kernel_launch(void* const* d_in, const int* in_sizes, int n_in,
                              void* d_out, int out_size, void* d_ws, size_t ws_size,
                              hipStream_t stream){
  const float* y        = (const float*)d_in[0];
  const float* s        = (const float*)d_in[1];
  const float* w_blue_s = (const float*)d_in[2];
  const float* w_blue_y = (const float*)d_in[3];
  const float* w_purple = (const float*)d_in[4];
  const float* rho_p    = (const float*)d_in[5];
  const float* gamma_p  = (const float*)d_in[6];
  const float* beta_p   = (const float*)d_in[7];
  const float* w_green  = (const float*)d_in[8];
  const float* rho_g    = (const float*)d_in[9];
  const float* gamma_g  = (const float*)d_in[10];
  const float* beta_g   = (const float*)d_in[11];
  float* out = (float*)d_out;
  float* ws  = (float*)d_ws;

  const int B = 2, SC = 128, N = 4096, NS = 16384;

  // ---- workspace layout (float units) ----
  unsigned short* s_peT = (unsigned short*)ws;                   // (dead after blue_s)
  unsigned short* y_peT = (unsigned short*)(ws + 2097152);
  unsigned short* yT    = (unsigned short*)(ws + 3145728);
  unsigned short* purple_h = (unsigned short*)ws;                // overlays s_peT
  unsigned short* qbuf_h = (unsigned short*)(ws + 4194304);
  unsigned short* vbuf_h = (unsigned short*)(ws + 4718592);
  unsigned short* mhaT   = (unsigned short*)(ws + 5242880);
  unsigned short* qk_bf  = (unsigned short*)(ws + 5767168);
  unsigned short* v_bf   = (unsigned short*)(ws + 6291456);
  unsigned short* green_h = (unsigned short*)(ws + 6815744);
  unsigned short* wffP_blues = (unsigned short*)(ws + 8912896);
  unsigned short* wffP_bluey = (unsigned short*)(ws + 8986624);
  unsigned short* wffF_green = (unsigned short*)(ws + 9134080);
  unsigned short* wffF_purple = (unsigned short*)(ws + 9396224);
  float* stats = ws + 9527296;   // upconv channel sums
  float* psum  = ws + 9528320;   // upconv partials [2][2][128][256]
  float* psq   = ws + 9659392;
  float* psumB = ws + 9790464;   // blue partials [2][2][128][64] = 32768
  float* psqB  = ws + 9823232;   // 32768

  dim3 blk(256);

  // 1) PE/transpose (y dual + s) + all weight repacks
  prep_all_kernel<<<dim3(1836), blk, 0, stream>>>(
      y, s, y_peT, yT, s_peT,
      w_blue_y, w_blue_s, w_green, w_purple,
      wffP_bluey, wffP_blues, wffF_green, wffF_purple);

  // 2) both blue convs (+ partial stats)
  conv_blue_kernel<<<dim3(64, 2, 4), blk, 0, stream>>>(
      y_peT, s_peT, wffP_bluey, wffP_blues, qbuf_h, vbuf_h, psumB, psqB);

  // 3) normalize+SiLU via partial stats; coalesced Q transpose + vectorized V
  qkv_transform_kernel<<<dim3(768), blk, 0, stream>>>(
      qbuf_h, vbuf_h, psumB, psqB, qk_bf, v_bf);

  // 4) MFMA flash attention (double-buffered) -> mhaT fp16 [b][N][128]
  flash_attn_kernel<<<dim3(N / 64, B * 4), dim3(1024), 0, stream>>>(qk_bf, v_bf, mhaT, N);

  // 5) both upsample convs (+ partial stats)
  conv_up_kernel<<<dim3(64, 2, 16), blk, 0, stream>>>(
      yT, mhaT, wffF_green, wffF_purple, green_h, purple_h, psum, psq);

  // 6) collapse upconv partials -> stats
  stats3_kernel<<<dim3(512), dim3(64), 0, stream>>>(psum, psq, stats);

  // 7) finalize
  iln_finalize2_kernel<<<dim3(8, B * SC, 2), blk, 0, stream>>>(
      green_h, purple_h, stats,
      rho_p, gamma_p, beta_p, rho_g, gamma_g, beta_g,
      s, out, NS, SC);
}

// Round 19
// 122.824 us; speedup vs baseline: 1.1409x; 1.1409x over previous
//
#include <hip/hip_runtime.h>
#include <math.h>

#define EPS 1e-5f

typedef __attribute__((ext_vector_type(8))) _Float16 f16x8;
typedef __attribute__((ext_vector_type(4))) float f32x4;
typedef __attribute__((ext_vector_type(2))) __fp16 fp16x2;

union H8u { ushort4 u[2]; uint4 q; f16x8 h; };
union PKu { fp16x2 h; unsigned int u; };
union U8u { unsigned short us[8]; uint4 q; };

__device__ __forceinline__ float sigmoidf_(float x){ return 1.f/(1.f+__expf(-x)); }

__device__ __forceinline__ unsigned short f2h(float f){
  union { _Float16 h; unsigned short u; } c;
  c.h = (_Float16)f;            // v_cvt_f16_f32, RNE
  return c.u;
}

// block-wide reduction of two accumulators; blockDim.x must be a multiple of 64
__device__ __forceinline__ void block_reduce2(float& s, float& s2){
  __shared__ float ls[16], ls2[16];
  #pragma unroll
  for (int off = 32; off; off >>= 1){
    s  += __shfl_down(s, off);
    s2 += __shfl_down(s2, off);
  }
  int wid = threadIdx.x >> 6, lane = threadIdx.x & 63;
  int nw = blockDim.x >> 6;
  if (lane == 0){ ls[wid] = s; ls2[wid] = s2; }
  __syncthreads();
  if (threadIdx.x == 0){
    float a = ls[0], b = ls2[0];
    for (int i = 1; i < nw; i++){ a += ls[i]; b += ls2[i]; }
    ls[0] = a; ls2[0] = b;
  }
  __syncthreads();
  s = ls[0]; s2 = ls2[0];
}

// ---- weight repack element generators ----
__device__ __forceinline__ unsigned short wffP_elem(const float* __restrict__ w, int Cin, int idx){
  int NCH = Cin >> 5;
  int per_tap = NCH << 9;
  int e = idx & 7, lane = (idx >> 3) & 63, chunk = (idx >> 9) % NCH;
  int tap = (idx / per_tap) % 9, coB = idx / (9 * per_tap);
  int lg = lane >> 4, lr = lane & 15;
  int co = coB * 16 + lr;
  int ch = chunk * 32 + ((e < 4) ? lg * 4 + e : 16 + lg * 4 + e - 4);
  return f2h(w[((long)co * Cin + ch) * 9 + tap]);
}

__device__ __forceinline__ unsigned short wffF_elem(const float* __restrict__ w, int Cin, int idx){
  int NCH = Cin >> 5;
  int per_tap = NCH << 9;
  int per_p = 8 * 4 * per_tap;
  int e = idx & 7, lane = (idx >> 3) & 63, chunk = (idx >> 9) % NCH;
  int tap = (idx / per_tap) % 4;
  int coB = (idx / (4 * per_tap)) % 8;
  int p = idx / per_p;
  int ph = p >> 1, pw = p & 1, kr = tap >> 1, kc = tap & 1;
  int lg = lane >> 4, lr = lane & 15;
  int co = coB * 16 + lr;
  int ch = chunk * 32 + ((e < 4) ? lg * 4 + e : 16 + lg * 4 + e - 4);
  const float* wb = &w[((long)co * Cin + ch) * 9];
  float sum = 0.f;
  for (int kh = 0; kh < 3; kh++){
    bool rok = (ph == 0) ? (kr == 0 ? kh == 0 : kh >= 1)
                         : (kr == 0 ? kh <= 1 : kh == 2);
    if (!rok) continue;
    for (int kw = 0; kw < 3; kw++){
      bool cok = (pw == 0) ? (kc == 0 ? kw == 0 : kw >= 1)
                           : (kc == 0 ? kw <= 1 : kw == 2);
      if (cok) sum += wb[kh * 3 + kw];
    }
  }
  return f2h(sum);
}

// Merged: PE/cast/transpose for y (dual) + s, AND all four weight repacks.
__global__ __launch_bounds__(256) void prep_all_kernel(
    const float* __restrict__ y, const float* __restrict__ s,
    unsigned short* __restrict__ y_peT, unsigned short* __restrict__ yT,
    unsigned short* __restrict__ s_peT,
    const float* __restrict__ wby, const float* __restrict__ wbs,
    const float* __restrict__ wg,  const float* __restrict__ wp,
    unsigned short* __restrict__ oby, unsigned short* __restrict__ obs,
    unsigned short* __restrict__ og,  unsigned short* __restrict__ op){
  __shared__ unsigned short tile[64][72];
  __shared__ unsigned short tile2[64][72];
  int bid = blockIdx.x;
  int tid = threadIdx.x;
  if (bid >= 1536){
    const int T0 = 294912, T1 = T0 + 147456, T2 = T1 + 524288, T3 = T2 + 262144;
    for (int idx = (bid - 1536) * 256 + tid; idx < T3; idx += 300 * 256){
      if (idx < T0)       oby[idx]      = wffP_elem(wby, 256, idx);
      else if (idx < T1)  obs[idx - T0] = wffP_elem(wbs, 128, idx - T0);
      else if (idx < T2)  og[idx - T1]  = wffF_elem(wg, 256, idx - T1);
      else                op[idx - T2]  = wffF_elem(wp, 128, idx - T2);
    }
    return;
  }
  const float* x; unsigned short *xt, *xt2;
  int C, L, half, bx, by, bz;
  if (bid < 512){
    x = y; xt = y_peT; xt2 = yT; C = 256; L = 4096; half = 128;
    bx = bid & 63; by = (bid >> 6) & 3; bz = bid >> 8;
  } else {
    int b2 = bid - 512;
    x = s; xt = s_peT; xt2 = nullptr; C = 128; L = 16384; half = 64;
    bx = b2 & 255; by = (b2 >> 8) & 1; bz = b2 >> 9;
  }
  int c0 = by * 64, l0 = bx * 64;
  int b = bz;
  const float l2r = 13.28771237954945f; // log2(10000)
  #pragma unroll
  for (int i = 0; i < 4; i++){
    int id = tid + i * 256;
    int c = id >> 4, ch = (id & 15) * 4;
    int cg = c0 + c;
    float4 v = *(const float4*)&x[((long)b * C + cg) * L + l0 + ch];
    int d = cg < half ? cg : cg - half;
    float rate = exp2f(-l2r * (float)d / (float)half);
    float a0 = (float)(l0 + ch) * rate;
    float pe0, pe1, pe2, pe3;
    if (cg < half){ pe0 = sinf(a0); pe1 = sinf(a0 + rate); pe2 = sinf(a0 + 2.f*rate); pe3 = sinf(a0 + 3.f*rate); }
    else          { pe0 = cosf(a0); pe1 = cosf(a0 + rate); pe2 = cosf(a0 + 2.f*rate); pe3 = cosf(a0 + 3.f*rate); }
    ushort4 o;
    o.x = f2h(v.x + pe0); o.y = f2h(v.y + pe1);
    o.z = f2h(v.z + pe2); o.w = f2h(v.w + pe3);
    *(ushort4*)&tile[c][ch] = o;
    if (xt2){
      ushort4 o2;
      o2.x = f2h(v.x); o2.y = f2h(v.y); o2.z = f2h(v.z); o2.w = f2h(v.w);
      *(ushort4*)&tile2[c][ch] = o2;
    }
  }
  __syncthreads();
  #pragma unroll
  for (int i = 0; i < 2; i++){
    int id = tid + i * 256;
    int l = id >> 3, ch = (id & 7) * 8;
    ushort4 a, bq;
    a.x = tile[ch+0][l]; a.y = tile[ch+1][l]; a.z = tile[ch+2][l]; a.w = tile[ch+3][l];
    bq.x = tile[ch+4][l]; bq.y = tile[ch+5][l]; bq.z = tile[ch+6][l]; bq.w = tile[ch+7][l];
    unsigned short* opt = &xt[((long)b * L + l0 + l) * C + c0 + ch];
    *(ushort4*)opt = a;
    *(ushort4*)(opt + 4) = bq;
    if (xt2){
      ushort4 a2, b2;
      a2.x = tile2[ch+0][l]; a2.y = tile2[ch+1][l]; a2.z = tile2[ch+2][l]; a2.w = tile2[ch+3][l];
      b2.x = tile2[ch+4][l]; b2.y = tile2[ch+5][l]; b2.z = tile2[ch+6][l]; b2.w = tile2[ch+7][l];
      unsigned short* op2 = &xt2[((long)b * L + l0 + l) * C + c0 + ch];
      *(ushort4*)op2 = a2;
      *(ushort4*)(op2 + 4) = b2;
    }
  }
}

// Implicit-GEMM MFMA conv body. Block = 4 waves, 64co x 64sp.
// STATS=1: per-block per-channel partial sum/sumsq (deterministic slots;
// partial stride 256 for UP convs, 64 for blues).
template<int NTAP, int CSHIFT, int UP, int STATS>
__device__ __forceinline__ void conv_body(
    const unsigned short* __restrict__ xt, const unsigned short* __restrict__ wff,
    unsigned short* __restrict__ out,
    float* __restrict__ psum, float* __restrict__ psq, int which,
    int Hin, int Win, int stride, int Wout, int woutLog, int HWout,
    int bz, char* stage, int* rowIdx){
  constexpr int Cin = 8 << CSHIFT;
  constexpr int NCHUNK = 1 << (CSHIFT - 2);
  constexpr int PSTRIDE = UP ? 256 : 64;
  int tid = threadIdx.x;
  int lane = tid & 63, wid = tid >> 6;
  int lg = lane >> 4, lr = lane & 15;
  int b, par = 0;
  if (UP){ par = bz & 3; b = bz >> 2; } else b = bz;
  const unsigned short* xb = xt + (long)b * Hin * Win * Cin;
  int coB = blockIdx.y * 4 + wid;

  if (UP){
    int ph = par >> 1, pw = par & 1;
    int ii = blockIdx.x;
    int VH = 2 * Hin, VW = 2 * Win;
    for (int id = tid; id < NTAP * 64; id += 256){
      int tap = id >> 6, r = id & 63;
      int kr = tap >> 1, kc = tap & 1;
      int v = 2 * ii + (ph == 0 ? (kr == 0 ? -1 : 0) : (kr == 0 ? 0 : 2));
      v = v < 0 ? -v : (v >= VH ? 2 * VH - 2 - v : v);
      int u = 2 * r + (pw == 0 ? (kc == 0 ? -1 : 0) : (kc == 0 ? 0 : 2));
      u = u < 0 ? -u : (u >= VW ? 2 * VW - 2 - u : u);
      rowIdx[tap * 64 + r] = (v >> 1) * Win + (u >> 1);
    }
  } else {
    int sp0 = blockIdx.x * 64;
    for (int id = tid; id < NTAP * 64; id += 256){
      int tap = id >> 6, r = id & 63;
      int kh = tap / 3, kw = tap - kh * 3;
      int sp = sp0 + r;
      int oh = sp >> woutLog, ow = sp & (Wout - 1);
      int ih = oh * stride - 1 + kh;
      ih = ih < 0 ? -ih : (ih >= Hin ? 2 * Hin - 2 - ih : ih);
      int iw = ow * stride - 1 + kw;
      iw = iw < 0 ? -iw : (iw >= Win ? 2 * Win - 2 - iw : iw);
      rowIdx[tap * 64 + r] = ih * Win + iw;
    }
  }

  f32x4 acc[4];
  #pragma unroll
  for (int f = 0; f < 4; f++) acc[f] = (f32x4){0.f, 0.f, 0.f, 0.f};

  const unsigned short* wbase =
      wff + ((long)((UP ? par : 0) * 8 + coB) * NTAP) * (NCHUNK * 512) + lane * 8;

  for (int tap = 0; tap < NTAP; tap++){
    __syncthreads();
    #pragma unroll
    for (int i2 = 0; i2 < NCHUNK; i2++){
      int id = tid + (i2 << 8);
      int sp = id >> CSHIFT;
      int c8 = (id & ((1 << CSHIFT) - 1)) << 3;
      int chunk = c8 >> 5, c = c8 & 31;
      int lgb = (c & 15) >> 2, hoff = (c >> 4) & 1;
      uint4 g = *(const uint4*)&xb[(long)rowIdx[tap * 64 + sp] * Cin + c8];
      int slot = ((chunk * 4 + (sp >> 4)) * 64 + lgb * 16 + (sp & 15)) * 16
                 + hoff * 8 + chunk * 16;
      *(uint2*)(stage + slot)       = make_uint2(g.x, g.y);
      *(uint2*)(stage + slot + 256) = make_uint2(g.z, g.w);
    }
    __syncthreads();
    const unsigned short* wp = wbase + (long)tap * (NCHUNK * 512);
    #pragma unroll
    for (int ch = 0; ch < NCHUNK; ch++){
      H8u A; A.q = *(const uint4*)(wp + ch * 512);
      #pragma unroll
      for (int f = 0; f < 4; f++){
        H8u X; X.q = *(const uint4*)(stage + ((ch * 4 + f) * 64 + lane) * 16 + ch * 16);
        acc[f] = __builtin_amdgcn_mfma_f32_16x16x32_f16(A.h, X.h, acc[f], 0, 0, 0);
      }
    }
  }

  unsigned short* ob = out + (long)b * 128 * HWout;
  #pragma unroll
  for (int f = 0; f < 4; f++){
    int spl = f * 16 + lr;
    long opos;
    if (UP){
      int oh = 2 * blockIdx.x + (par >> 1);
      int ow = 2 * spl + (par & 1);
      opos = (long)oh * Wout + ow;
    } else opos = (long)blockIdx.x * 64 + spl;
    #pragma unroll
    for (int r = 0; r < 4; r++){
      int co = coB * 16 + lg * 4 + r;
      ob[(long)co * HWout + opos] = f2h(acc[f][r]);
    }
  }

  if constexpr (STATS){
    float ts[4], tq[4];
    #pragma unroll
    for (int r = 0; r < 4; r++){ ts[r] = 0.f; tq[r] = 0.f; }
    #pragma unroll
    for (int f = 0; f < 4; f++)
      #pragma unroll
      for (int r = 0; r < 4; r++){
        float hv = (float)(_Float16)acc[f][r];
        ts[r] += hv; tq[r] += hv * hv;
      }
    #pragma unroll
    for (int off = 1; off < 16; off <<= 1){
      #pragma unroll
      for (int r = 0; r < 4; r++){
        ts[r] += __shfl_xor(ts[r], off);
        tq[r] += __shfl_xor(tq[r], off);
      }
    }
    if (lr == 0){
      int strip = UP ? (blockIdx.x * 4 + par) : blockIdx.x;
      #pragma unroll
      for (int r = 0; r < 4; r++){
        int co = coB * 16 + lg * 4 + r;
        long pidx = (((long)which * 2 + b) * 128 + co) * PSTRIDE + strip;
        psum[pidx] = ts[r];
        psq[pidx]  = tq[r];
      }
    }
  }
}

// Merged blue convs (+ partial stats): grid (64, 2, 4); z<2 -> blue_y, else blue_s.
__global__ __launch_bounds__(256) void conv_blue_kernel(
    const unsigned short* __restrict__ y_peT, const unsigned short* __restrict__ s_peT,
    const unsigned short* __restrict__ wby, const unsigned short* __restrict__ wbs,
    unsigned short* __restrict__ qbuf, unsigned short* __restrict__ vbuf,
    float* __restrict__ psumB, float* __restrict__ psqB){
  __shared__ __align__(16) char stage[8 * 4112];
  __shared__ int rowIdx[9 * 64];
  int z = blockIdx.z;
  if (z < 2)
    conv_body<9,5,0,1>(y_peT, wby, qbuf, psumB, psqB, 0,
                       64, 64, 1, 64, 6, 4096, z, stage, rowIdx);
  else
    conv_body<9,4,0,1>(s_peT, wbs, vbuf, psumB, psqB, 1,
                       128, 128, 2, 64, 6, 4096, z - 2, stage, rowIdx);
}

// Merged upsample convs (+partial stats): grid (64, 2, 16); z<8 -> green, else purple.
__global__ __launch_bounds__(256) void conv_up_kernel(
    const unsigned short* __restrict__ yT, const unsigned short* __restrict__ mhaT,
    const unsigned short* __restrict__ wg, const unsigned short* __restrict__ wp,
    unsigned short* __restrict__ green_h, unsigned short* __restrict__ purple_h,
    float* __restrict__ psum, float* __restrict__ psq){
  __shared__ __align__(16) char stage[8 * 4112];
  __shared__ int rowIdx[4 * 64];
  int z = blockIdx.z;
  if (z < 8)
    conv_body<4,5,1,1>(yT, wg, green_h, psum, psq, 0,
                       64, 64, 1, 128, 7, 16384, z, stage, rowIdx);
  else
    conv_body<4,4,1,1>(mhaT, wp, purple_h, psum, psq, 1,
                       64, 64, 1, 128, 7, 16384, z - 8, stage, rowIdx);
}

// Normalize+SiLU using conv_blue's partial stats (no data re-read for stats).
// blocks [0,256): Q path -> coalesced transposed write via LDS tile.
// blocks [256,768): V path -> vectorized channel-major write.
__global__ __launch_bounds__(256) void qkv_transform_kernel(
    const unsigned short* __restrict__ qbuf, const unsigned short* __restrict__ vbuf,
    const float* __restrict__ psumB, const float* __restrict__ psqB,
    unsigned short* __restrict__ outT, unsigned short* __restrict__ outV){
  int bid = blockIdx.x;
  int tid = threadIdx.x;
  if (bid < 256){
    __shared__ unsigned short tile[32][137];
    __shared__ float sm[32], sr[32];
    int pt = bid & 31, h = (bid >> 5) & 3, bb = bid >> 7;
    int c_local = tid >> 3, i0 = tid & 7;
    int cg = h * 32 + c_local;
    long base = ((long)bb * 128 + cg) * 64;     // which=0 group = bb
    float s = 0.f, s2 = 0.f;
    #pragma unroll
    for (int k = 0; k < 8; k++){
      s  += psumB[base + i0 + k * 8];
      s2 += psqB[base + i0 + k * 8];
    }
    #pragma unroll
    for (int off = 1; off < 8; off <<= 1){
      s  += __shfl_xor(s, off);
      s2 += __shfl_xor(s2, off);
    }
    if (i0 == 0){
      float mean = s * (1.f / 4096.f);
      float var  = s2 * (1.f / 4096.f) - mean * mean;
      sm[c_local] = mean;
      sr[c_local] = rsqrtf(var + EPS);
    }
    __syncthreads();
    float mean = sm[c_local], rstd = sr[c_local];
    const unsigned short* qp = qbuf + ((long)bb * 128 + cg) * 4096 + pt * 128 + i0 * 16;
    H8u a, b2;
    a.q  = *(const uint4*)qp;
    b2.q = *(const uint4*)(qp + 8);
    #pragma unroll
    for (int j = 0; j < 8; j++){
      float t0 = ((float)a.h[j] - mean) * rstd;
      tile[c_local][i0 * 16 + j] = f2h(t0 * sigmoidf_(t0));
      float t1 = ((float)b2.h[j] - mean) * rstd;
      tile[c_local][i0 * 16 + 8 + j] = f2h(t1 * sigmoidf_(t1));
    }
    __syncthreads();
    int pos = tid >> 1, halfd = tid & 1;
    U8u w0, w1;
    #pragma unroll
    for (int k = 0; k < 8; k++) w0.us[k] = tile[halfd * 16 + k][pos];
    #pragma unroll
    for (int k = 0; k < 8; k++) w1.us[k] = tile[halfd * 16 + 8 + k][pos];
    unsigned short* op = outT + ((long)((bb * 4 + h) * 4096 + pt * 128 + pos)) * 32 + halfd * 16;
    *(uint4*)op = w0.q;
    *(uint4*)(op + 8) = w1.q;
  } else {
    int vb = bid - 256;                 // 0..511; two blocks per channel
    int bc = vb >> 1;
    long gbase = ((long)(2 + (bc >> 7)) * 128 + (bc & 127)) * 64;  // which=1
    float s = 0.f, s2 = 0.f;
    if (tid < 64){ s = psumB[gbase + tid]; s2 = psqB[gbase + tid]; }
    block_reduce2(s, s2);
    float mean = s * (1.f / 4096.f);
    float var  = s2 * (1.f / 4096.f) - mean * mean;
    float rstd = rsqrtf(var + EPS);
    long e0 = (long)vb * 2048 + tid * 8;
    H8u a; a.q = *(const uint4*)&vbuf[e0];
    H8u o;
    #pragma unroll
    for (int j = 0; j < 8; j++){
      float t = ((float)a.h[j] - mean) * rstd;
      o.h[j] = (_Float16)(t * sigmoidf_(t));
    }
    *(uint4*)&outV[e0] = o.q;
  }
}

// MFMA flash attention (fp16), 4-way key-split, 64-key tiles, LDS double-buffer
// + V-XOR de-conflict + defer-max + pre-scaled Q (r17-proven softmax form).
__global__ __launch_bounds__(1024, 8) void flash_attn_kernel(
    const unsigned short* __restrict__ qk,
    const unsigned short* __restrict__ vt,
    unsigned short* __restrict__ mhaT, int N){
  __shared__ float smem[16384];                // 64 KB: 2 x (4 splits x 8KB)
  unsigned short* sstage = (unsigned short*)smem;
  const float SCALE2 = 0.25503257066404493f;   // (1/sqrt(32)) * log2(e)

  int bh = blockIdx.y;
  int b = bh >> 2, h = bh & 3;
  int tid = threadIdx.x;
  int ks = tid >> 8;                 // key-split 0..3
  int t256 = tid & 255;
  int qg = (tid >> 6) & 3;           // query-group within split
  int lane = tid & 63;
  int lg = lane >> 4, lr = lane & 15;
  const unsigned short* qbase = qk + (long)bh * N * 32;
  const unsigned short* vbase = vt + (long)(b * 128 + h * 32) * N;
  int ksu = ks * 4096;               // ushort offset of this split's 8KB stage

  int q0w = blockIdx.x * 64 + qg * 16;
  f16x8 qf;
  {
    const unsigned short* qp = qbase + (long)(q0w + lr) * 32 + lg * 4;
    H8u Q;
    Q.u[0] = *(const ushort4*)qp;
    Q.u[1] = *(const ushort4*)(qp + 16);
    qf = Q.h;
    const _Float16 sc = (_Float16)SCALE2;
    #pragma unroll
    for (int j = 0; j < 8; j++) qf[j] = qf[j] * sc;
  }

  int skey = t256 >> 2, sq4 = t256 & 3;        // K: key row, d-quarter (2-way = free)
  int kdst = ksu + (((skey >> 4) * 4 + (sq4 & 1) * 2) * 16 + (skey & 15)) * 8 + (sq4 >> 1) * 4;
  int sd = t256 >> 3, soct = t256 & 7;         // V: d row, key-octet
  int vx = (soct >> 2) * 2 + (soct & 1);
  int vdst = ksu + 2048 +
      ((((soct >> 2) * 2 + (sd >> 4)) * 4 + (soct & 1) * 2) * 16 + ((sd & 15) ^ vx)) * 8 +
      ((soct >> 1) & 1) * 4;

  float m_run = -1e30f, l_run = 0.f;
  f32x4 acc0 = {0.f,0.f,0.f,0.f}, acc1 = {0.f,0.f,0.f,0.f};

  const int NT = N >> 8;                       // 64-key tiles per split

  // prologue: stage tile 0 into buffer 0
  {
    int k0 = ks * NT * 64;
    uint4 kl = *(const uint4*)(qbase + (long)(k0 + skey) * 32 + sq4 * 8);
    *(uint2*)(&sstage[kdst])       = make_uint2(kl.x, kl.y);
    *(uint2*)(&sstage[kdst + 128]) = make_uint2(kl.z, kl.w);
    uint4 vl = *(const uint4*)(vbase + (long)sd * N + k0 + soct * 8);
    *(uint2*)(&sstage[vdst])       = make_uint2(vl.x, vl.y);
    *(uint2*)(&sstage[vdst + 128]) = make_uint2(vl.z, vl.w);
  }
  __syncthreads();

  for (int t = 0; t < NT; t++){
    int bufc = (t & 1) << 14;                  // 16384 ushorts per buffer
    int bufn = ((t + 1) & 1) << 14;
    uint4 kl, vl;
    bool have_next = (t + 1 < NT);
    if (have_next){
      int k0n = (ks * NT + t + 1) * 64;
      kl = *(const uint4*)(qbase + (long)(k0n + skey) * 32 + sq4 * 8);
      vl = *(const uint4*)(vbase + (long)sd * N + k0n + soct * 8);
    }

    // compute tile t from buffer bufc
    f32x4 st[4];
    #pragma unroll
    for (int kb = 0; kb < 4; kb++){
      H8u K;
      K.q = *(const uint4*)(&sstage[bufc + ksu + (kb * 64 + lane) * 8]);
      st[kb] = __builtin_amdgcn_mfma_f32_16x16x32_f16(K.h, qf,
                  (f32x4){0.f,0.f,0.f,0.f}, 0, 0, 0);
    }

    float mk0 = fmaxf(fmaxf(fmaxf(st[0][0], st[0][1]), st[0][2]), st[0][3]);
    float mk1 = fmaxf(fmaxf(fmaxf(st[1][0], st[1][1]), st[1][2]), st[1][3]);
    float mk2 = fmaxf(fmaxf(fmaxf(st[2][0], st[2][1]), st[2][2]), st[2][3]);
    float mk3 = fmaxf(fmaxf(fmaxf(st[3][0], st[3][1]), st[3][2]), st[3][3]);
    float mt = fmaxf(fmaxf(fmaxf(mk0, mk1), mk2), mk3);
    mt = fmaxf(mt, __shfl_xor(mt, 16));
    mt = fmaxf(mt, __shfl_xor(mt, 32));

    bool noresc = __all(mt <= m_run + 8.f);
    float m_new = noresc ? m_run : fmaxf(m_run, mt);

    float lt = 0.f;
    unsigned int pup[8];
    #pragma unroll
    for (int kb = 0; kb < 4; kb++)
      #pragma unroll
      for (int rp = 0; rp < 2; rp++){
        float p0 = __builtin_amdgcn_exp2f(st[kb][2*rp]   - m_new);
        float p1 = __builtin_amdgcn_exp2f(st[kb][2*rp+1] - m_new);
        lt += p0 + p1;
        PKu pk;
        pk.h = __builtin_amdgcn_cvt_pkrtz(p0, p1);
        pup[kb * 2 + rp] = pk.u;
      }
    lt += __shfl_xor(lt, 16);
    lt += __shfl_xor(lt, 32);

    if (noresc){
      l_run += lt;
    } else {
      float fscale = __builtin_amdgcn_exp2f(m_run - m_new);
      l_run = l_run * fscale + lt;
      float fr[4];
      #pragma unroll
      for (int r = 0; r < 4; r++) fr[r] = __shfl(fscale, lg * 4 + r);
      #pragma unroll
      for (int r = 0; r < 4; r++){ acc0[r] *= fr[r]; acc1[r] *= fr[r]; }
      m_run = m_new;
    }

    #pragma unroll
    for (int m = 0; m < 2; m++){
      int xr = m * 2 + (lg >> 1);
      int laneV = lg * 16 + (lr ^ xr);
      H8u P, V0, V1;
      P.q = make_uint4(pup[4*m], pup[4*m+1], pup[4*m+2], pup[4*m+3]);
      V0.q = *(const uint4*)(&sstage[bufc + ksu + 2048 + ((m * 2 + 0) * 64 + laneV) * 8]);
      V1.q = *(const uint4*)(&sstage[bufc + ksu + 2048 + ((m * 2 + 1) * 64 + laneV) * 8]);
      acc0 = __builtin_amdgcn_mfma_f32_16x16x32_f16(P.h, V0.h, acc0, 0, 0, 0);
      acc1 = __builtin_amdgcn_mfma_f32_16x16x32_f16(P.h, V1.h, acc1, 0, 0, 0);
    }

    // stage tile t+1 into the other buffer, then one barrier
    if (have_next){
      *(uint2*)(&sstage[bufn + kdst])       = make_uint2(kl.x, kl.y);
      *(uint2*)(&sstage[bufn + kdst + 128]) = make_uint2(kl.z, kl.w);
      *(uint2*)(&sstage[bufn + vdst])       = make_uint2(vl.x, vl.y);
      *(uint2*)(&sstage[bufn + vdst + 128]) = make_uint2(vl.z, vl.w);
    }
    __syncthreads();
  }

  // ---- split merge in LDS ----
  float* accM = smem;                          // [qg][ks][16 q][33]
  float* mM   = smem + 8448;
  float* lM   = smem + 8704;
  #pragma unroll
  for (int r = 0; r < 4; r++){
    accM[((qg * 4 + ks) * 16 + (lg * 4 + r)) * 33 + lr]      = acc0[r];
    accM[((qg * 4 + ks) * 16 + (lg * 4 + r)) * 33 + 16 + lr] = acc1[r];
  }
  if (lg == 0){
    mM[(qg * 4 + ks) * 16 + lr] = m_run;
    lM[(qg * 4 + ks) * 16 + lr] = l_run;
  }
  __syncthreads();
  if (ks == 0){
    int q = lane >> 2, dc = lane & 3;
    float ms[4], es[4];
    float m = -1e30f;
    #pragma unroll
    for (int s = 0; s < 4; s++){ ms[s] = mM[(qg * 4 + s) * 16 + q]; m = fmaxf(m, ms[s]); }
    float l = 0.f;
    #pragma unroll
    for (int s = 0; s < 4; s++){
      es[s] = __builtin_amdgcn_exp2f(ms[s] - m);
      l += lM[(qg * 4 + s) * 16 + q] * es[s];
    }
    float inv = 1.f / l;
    float o[8];
    #pragma unroll
    for (int j = 0; j < 8; j++) o[j] = 0.f;
    #pragma unroll
    for (int s = 0; s < 4; s++){
      const float* ap = &accM[((qg * 4 + s) * 16 + q) * 33 + dc * 8];
      #pragma unroll
      for (int j = 0; j < 8; j++) o[j] += ap[j] * es[s];
    }
    ushort4 o0, o1;
    o0.x = f2h(o[0]*inv); o0.y = f2h(o[1]*inv); o0.z = f2h(o[2]*inv); o0.w = f2h(o[3]*inv);
    o1.x = f2h(o[4]*inv); o1.y = f2h(o[5]*inv); o1.z = f2h(o[6]*inv); o1.w = f2h(o[7]*inv);
    unsigned short* op = &mhaT[((long)b * N + q0w + q) * 128 + h * 32 + dc * 8];
    *(ushort4*)op = o0;
    *(ushort4*)(op + 4) = o1;
  }
}

// Collapse per-block upconv partials (deterministic)
__global__ __launch_bounds__(64) void stats3_kernel(
    const float* __restrict__ psum, const float* __restrict__ psq,
    float* __restrict__ statsbase){
  int blockch = blockIdx.x;
  int which = blockch >> 8, bc = blockch & 255;
  const float* ps = psum + (long)blockch * 256;
  const float* pq = psq  + (long)blockch * 256;
  float s = 0.f, s2 = 0.f;
  for (int i = threadIdx.x; i < 256; i += 64){ s += ps[i]; s2 += pq[i]; }
  #pragma unroll
  for (int off = 32; off; off >>= 1){
    s  += __shfl_down(s, off);
    s2 += __shfl_down(s2, off);
  }
  if (threadIdx.x == 0){
    float* sums = statsbase + which * 512;
    sums[bc] = s;
    sums[256 + bc] = s2;
  }
}

// Merged ILN finalize: blockIdx.z = 0 -> purple (sigmoid*gate), 1 -> green (silu).
__global__ __launch_bounds__(256) void iln_finalize2_kernel(
    const unsigned short* __restrict__ xg, const unsigned short* __restrict__ xp,
    const float* __restrict__ statsbase,
    const float* __restrict__ rho_p, const float* __restrict__ gamma_p,
    const float* __restrict__ beta_p,
    const float* __restrict__ rho_g, const float* __restrict__ gamma_g,
    const float* __restrict__ beta_g,
    const float* __restrict__ gate,
    float* __restrict__ out,
    int HW, int C){
  int zp = blockIdx.z;                 // 0 = purple, 1 = green
  int bc = blockIdx.y;
  int b = bc / C, c = bc % C;
  const float* sums   = statsbase + (zp ? 0 : 512);   // green at +0, purple at +512
  const float* sumsqs = sums + 256;

  // inline layer reduction over C channels of batch b
  float s = 0.f, s2 = 0.f;
  if (threadIdx.x < 128){
    int cc = b * C + threadIdx.x;
    s = sums[cc]; s2 = sumsqs[cc];
  }
  block_reduce2(s, s2);
  float lsum = s, lsumsq = s2;

  float n = (float)HW;
  float im = sums[bc] / n;
  float iv = (sumsqs[bc] / n - im * im) * (n / (n - 1.f));
  float ir = rsqrtf(iv + EPS);
  float n2 = n * (float)C;
  float lm = lsum / n2;
  float lv = (lsumsq / n2 - lm * lm) * (n2 / (n2 - 1.f));
  float lr = rsqrtf(lv + EPS);
  float r  = zp ? rho_g[c]   : rho_p[c];
  float g  = zp ? gamma_g[c] : gamma_p[c];
  float bb = zp ? beta_g[c]  : beta_p[c];

  const unsigned short* xp_ = (zp ? xg : xp) + (long)bc * HW;
  const float* gp = zp ? nullptr : (gate + (long)bc * HW);
  float* op = out + ((long)(b * 256 + (zp ? 128 : 0) + c)) * HW;
  int i0 = (blockIdx.x * 256 + threadIdx.x) * 8;
  H8u a; a.q = *(const uint4*)&xp_[i0];
  float4 o0, o1;
  float res[8];
  #pragma unroll
  for (int j = 0; j < 8; j++){
    float xv = (float)a.h[j];
    float t = r * (xv - im) * ir + (1.f - r) * (xv - lm) * lr;
    t = t * g + bb;
    float sg = sigmoidf_(t);
    res[j] = zp ? t * sg : sg;
  }
  if (!zp){
    float4 g0 = *(const float4*)&gp[i0];
    float4 g1 = *(const float4*)&gp[i0 + 4];
    res[0] *= g0.x; res[1] *= g0.y; res[2] *= g0.z; res[3] *= g0.w;
    res[4] *= g1.x; res[5] *= g1.y; res[6] *= g1.z; res[7] *= g1.w;
  }
  o0.x = res[0]; o0.y = res[1]; o0.z = res[2]; o0.w = res[3];
  o1.x = res[4]; o1.y = res[5]; o1.z = res[6]; o1.w = res[7];
  *(float4*)&op[i0] = o0;
  *(float4*)&op[i0 + 4] = o1;
}

extern "C" void kernel_launch(void* const* d_in, const int* in_sizes, int n_in,
                              void* d_out, int out_size, void* d_ws, size_t ws_size,
                              hipStream_t stream){
  const float* y        = (const float*)d_in[0];
  const float* s        = (const float*)d_in[1];
  const float* w_blue_s = (const float*)d_in[2];
  const float* w_blue_y = (const float*)d_in[3];
  const float* w_purple = (const float*)d_in[4];
  const float* rho_p    = (const float*)d_in[5];
  const float* gamma_p  = (const float*)d_in[6];
  const float* beta_p   = (const float*)d_in[7];
  const float* w_green  = (const float*)d_in[8];
  const float* rho_g    = (const float*)d_in[9];
  const float* gamma_g  = (const float*)d_in[10];
  const float* beta_g   = (const float*)d_in[11];
  float* out = (float*)d_out;
  float* ws  = (float*)d_ws;

  const int B = 2, SC = 128, N = 4096, NS = 16384;

  // ---- workspace layout (float units) ----
  unsigned short* s_peT = (unsigned short*)ws;                   // (dead after blue_s)
  unsigned short* y_peT = (unsigned short*)(ws + 2097152);
  unsigned short* yT    = (unsigned short*)(ws + 3145728);
  unsigned short* purple_h = (unsigned short*)ws;                // overlays s_peT
  unsigned short* qbuf_h = (unsigned short*)(ws + 4194304);
  unsigned short* vbuf_h = (unsigned short*)(ws + 4718592);
  unsigned short* mhaT   = (unsigned short*)(ws + 5242880);
  unsigned short* qk_bf  = (unsigned short*)(ws + 5767168);
  unsigned short* v_bf   = (unsigned short*)(ws + 6291456);
  unsigned short* green_h = (unsigned short*)(ws + 6815744);
  unsigned short* wffP_blues = (unsigned short*)(ws + 8912896);
  unsigned short* wffP_bluey = (unsigned short*)(ws + 8986624);
  unsigned short* wffF_green = (unsigned short*)(ws + 9134080);
  unsigned short* wffF_purple = (unsigned short*)(ws + 9396224);
  float* stats = ws + 9527296;   // upconv channel sums
  float* psum  = ws + 9528320;   // upconv partials [2][2][128][256]
  float* psq   = ws + 9659392;
  float* psumB = ws + 9790464;   // blue partials [2][2][128][64] = 32768
  float* psqB  = ws + 9823232;   // 32768

  dim3 blk(256);

  // 1) PE/transpose (y dual + s) + all weight repacks
  prep_all_kernel<<<dim3(1836), blk, 0, stream>>>(
      y, s, y_peT, yT, s_peT,
      w_blue_y, w_blue_s, w_green, w_purple,
      wffP_bluey, wffP_blues, wffF_green, wffF_purple);

  // 2) both blue convs (+ partial stats)
  conv_blue_kernel<<<dim3(64, 2, 4), blk, 0, stream>>>(
      y_peT, s_peT, wffP_bluey, wffP_blues, qbuf_h, vbuf_h, psumB, psqB);

  // 3) normalize+SiLU via partial stats; coalesced Q transpose + vectorized V
  qkv_transform_kernel<<<dim3(768), blk, 0, stream>>>(
      qbuf_h, vbuf_h, psumB, psqB, qk_bf, v_bf);

  // 4) MFMA flash attention (double-buffered) -> mhaT fp16 [b][N][128]
  flash_attn_kernel<<<dim3(N / 64, B * 4), dim3(1024), 0, stream>>>(qk_bf, v_bf, mhaT, N);

  // 5) both upsample convs (+ partial stats)
  conv_up_kernel<<<dim3(64, 2, 16), blk, 0, stream>>>(
      yT, mhaT, wffF_green, wffF_purple, green_h, purple_h, psum, psq);

  // 6) collapse upconv partials -> stats
  stats3_kernel<<<dim3(512), dim3(64), 0, stream>>>(psum, psq, stats);

  // 7) finalize
  iln_finalize2_kernel<<<dim3(8, B * SC, 2), blk, 0, stream>>>(
      green_h, purple_h, stats,
      rho_p, gamma_p, beta_p, rho_g, gamma_g, beta_g,
      s, out, NS, SC);
}